// Round 7
// baseline (1523.031 us; speedup 1.0000x reference)
//
#include <hip/hip_runtime.h>

#define EPS 1e-5f
#define NTHR 256
#define NBLK 1024
#define NSLOT 8

typedef __bf16 bf16x8 __attribute__((ext_vector_type(8)));
typedef float f32x16 __attribute__((ext_vector_type(16)));

// d_ws layout:
//   [0, N*32)            bf16 x, tile-major MFMA B-frag order: xb[(t*64+lane)*8..+8)
//   [N*32, +6144)        stats slots: layer L: stats[L*512 + slot*64 + idx]
//                        idx 0..31 = sum(z_L), 32..63 = sum(z_L^2)
//   [N*32+6144, +4)      barrier counter
//
// 32x32x16 bf16 MFMA layouts (m74/m101-verified):
//   C/D: col=lane&31 (data row), row p=(reg&3)+8*(reg>>2)+4h, h=lane>>5
//   A/B: m|n=lane&31, k=8h+j
// Acc regs 0..7/8..15 feed the next layer's B-frag; next-layer weights use
// columns permuted by phi(K)=(j&3)+8*(j>>2)+4h+16*kh. BN scale a>0 folds into
// next-layer weight columns; shift e=b-mu+be/a folds into the C-init.
//
// Round-7: single fused kernel. __launch_bounds__(256,4) caps VGPR at 128 =>
// 4 blocks/CU guaranteed => all NBLK=1024 blocks co-resident => atomic
// barrier is deadlock-free (R4 failed at 2 waves/SIMD; this runs 4), and the
// kernel's rocprof counters finally become visible over the 77us poison fills.

__device__ __forceinline__ void gbarrier(unsigned* cnt, unsigned target, int tid) {
    __syncthreads();
    __threadfence();   // release: drain stores, L2 writeback (cross-XCD)
    if (tid == 0) {
        __hip_atomic_fetch_add(cnt, 1u, __ATOMIC_ACQ_REL, __HIP_MEMORY_SCOPE_AGENT);
        while (__hip_atomic_load(cnt, __ATOMIC_ACQUIRE, __HIP_MEMORY_SCOPE_AGENT) < target)
            __builtin_amdgcn_s_sleep(8);
    }
    __syncthreads();
    __threadfence();   // acquire
}

__global__ __launch_bounds__(NTHR, 4) void k_all(
    const float* __restrict__ x, __bf16* __restrict__ xb,
    const float* __restrict__ W1, const float* __restrict__ b1,
    const float* __restrict__ g1, const float* __restrict__ be1,
    const float* __restrict__ W2, const float* __restrict__ b2,
    const float* __restrict__ g2, const float* __restrict__ be2,
    const float* __restrict__ W3, const float* __restrict__ b3,
    const float* __restrict__ g3, const float* __restrict__ be3,
    const float* __restrict__ W4, const float* __restrict__ b4,
    float* __restrict__ stats, unsigned* __restrict__ cnt,
    float* __restrict__ out, int N)
{
    __shared__ float s_a[32], s_e[32], s_b[64];

    const int tid  = threadIdx.x;
    const int lane = tid & 63;
    const int h    = lane >> 5;
    const int ml   = lane & 31;
    const float invN = 1.0f / (float)N;

    const int ntiles = N >> 5;                 // 65536
    const int nwaves = NBLK * (NTHR / 64);     // 4096
    const int gwave  = blockIdx.x * (NTHR / 64) + (tid >> 6);
    const int K      = ntiles / nwaves;        // 16

    float sums[16], sqs[16];

    auto zero_acc = [&]() {
        #pragma unroll
        for (int i = 0; i < 16; ++i) { sums[i] = 0.f; sqs[i] = 0.f; }
    };
    auto accum2 = [&](const f32x16& A, const f32x16& B) {
        #pragma unroll
        for (int i = 0; i < 16; ++i) {
            sums[i] += A[i] + B[i];
            sqs[i]  = fmaf(A[i], A[i], fmaf(B[i], B[i], sqs[i]));
        }
    };
    auto accum1 = [&](const f32x16& A) {
        #pragma unroll
        for (int i = 0; i < 16; ++i) { sums[i] += A[i]; sqs[i] = fmaf(A[i], A[i], sqs[i]); }
    };
    auto rp = [&](const f32x16& a, bf16x8& lo, bf16x8& hi) {
        #pragma unroll
        for (int j = 0; j < 8; ++j) {
            lo[j] = (__bf16)fmaxf(a[j], 0.f);
            hi[j] = (__bf16)fmaxf(a[8 + j], 0.f);
        }
    };
    auto flush = [&](int L) {
        __syncthreads();
        if (tid < 64) s_b[tid] = 0.f;
        __syncthreads();
        #pragma unroll
        for (int i = 0; i < 16; ++i) {
            float s = sums[i], q = sqs[i];
            #pragma unroll
            for (int d = 1; d <= 16; d <<= 1) { s += __shfl_xor(s, d); q += __shfl_xor(q, d); }
            if (ml == 0) {
                int p = (i & 3) + 8 * (i >> 2) + 4 * h;
                atomicAdd(&s_b[p], s);
                atomicAdd(&s_b[32 + p], q);
            }
        }
        __syncthreads();
        if (tid < 64)
            atomicAdd(&stats[L * (NSLOT * 64) + (blockIdx.x & (NSLOT - 1)) * 64 + tid], s_b[tid]);
    };
    auto derive = [&](int L, const float* g, const float* be, const float* b) {
        if (tid < 64) {
            float t2 = 0.f;
            #pragma unroll
            for (int s = 0; s < NSLOT; ++s)
                t2 += __hip_atomic_load(&stats[L * (NSLOT * 64) + s * 64 + tid],
                                        __ATOMIC_RELAXED, __HIP_MEMORY_SCOPE_AGENT);
            s_b[tid] = t2;
        }
        __syncthreads();
        if (tid < 32) {
            float mu = s_b[tid] * invN;
            float v  = s_b[32 + tid] * invN - mu * mu;
            float a  = g[tid] * rsqrtf(v + EPS);
            s_a[tid] = a;
            s_e[tid] = b[tid] - mu + be[tid] / a;
        }
        __syncthreads();
    };
    auto loadxb = [&](int t) -> bf16x8 {
        return *(const bf16x8*)(xb + ((size_t)t * 64 + lane) * 8);
    };
    auto build_wf = [&](const float* W, bf16x8& f0, bf16x8& f1) {
        #pragma unroll
        for (int kh = 0; kh < 2; ++kh)
            #pragma unroll
            for (int j = 0; j < 8; ++j) {
                int pk = (j & 3) + 8 * (j >> 2) + 4 * h + 16 * kh;
                float v = W[ml * 32 + pk] * s_a[pk];
                if (kh == 0) f0[j] = (__bf16)v; else f1[j] = (__bf16)v;
            }
    };

    // ================= Phase 1: x -> xb, stats(z1) =================
    bf16x8 w1f;
    {
        const float* p = W1 + ml * 16 + h * 8;
        #pragma unroll
        for (int j = 0; j < 8; ++j) w1f[j] = (__bf16)p[j];
    }
    f32x16 c1;
    #pragma unroll
    for (int i = 0; i < 16; ++i) c1[i] = b1[(i & 3) + 8 * (i >> 2) + 4 * h];

    zero_acc();
    {
        auto loadraw = [&](int t, float4& u0, float4& u1) {
            const float4* xp = (const float4*)(x + (size_t)((t << 5) + ml) * 16 + h * 8);
            u0 = xp[0]; u1 = xp[1];
        };
        auto cvt = [&](const float4& u0, const float4& u1) -> bf16x8 {
            bf16x8 xf;
            xf[0] = (__bf16)u0.x; xf[1] = (__bf16)u0.y; xf[2] = (__bf16)u0.z; xf[3] = (__bf16)u0.w;
            xf[4] = (__bf16)u1.x; xf[5] = (__bf16)u1.y; xf[6] = (__bf16)u1.z; xf[7] = (__bf16)u1.w;
            return xf;
        };
        float4 a0, a1, b0, b1v, p0, p1, q0, q1;
        int i = 0;
        if (K >= 2) {
            loadraw(gwave, a0, a1);
            loadraw(gwave + nwaves, b0, b1v);
            for (; i + 1 < K; i += 2) {
                int t0 = gwave + i * nwaves;
                if (i + 3 < K) {
                    loadraw(t0 + 2 * nwaves, p0, p1);
                    loadraw(t0 + 3 * nwaves, q0, q1);
                }
                bf16x8 xf0 = cvt(a0, a1);
                bf16x8 xf1 = cvt(b0, b1v);
                *(bf16x8*)(xb + ((size_t)t0 * 64 + lane) * 8) = xf0;
                *(bf16x8*)(xb + ((size_t)(t0 + nwaves) * 64 + lane) * 8) = xf1;
                f32x16 A1 = __builtin_amdgcn_mfma_f32_32x32x16_bf16(w1f, xf0, c1, 0, 0, 0);
                f32x16 B1 = __builtin_amdgcn_mfma_f32_32x32x16_bf16(w1f, xf1, c1, 0, 0, 0);
                accum2(A1, B1);
                a0 = p0; a1 = p1; b0 = q0; b1v = q1;
            }
        }
        for (int t = gwave + i * nwaves; t < ntiles; t += nwaves) {   // tail
            float4 u0, u1;
            loadraw(t, u0, u1);
            bf16x8 xf = cvt(u0, u1);
            *(bf16x8*)(xb + ((size_t)t * 64 + lane) * 8) = xf;
            accum1(__builtin_amdgcn_mfma_f32_32x32x16_bf16(w1f, xf, c1, 0, 0, 0));
        }
    }
    flush(0);
    gbarrier(cnt, NBLK, tid);
    derive(0, g1, be1, b1);

    bf16x8 w2f0, w2f1;
    build_wf(W2, w2f0, w2f1);
    f32x16 c2;
    #pragma unroll
    for (int i = 0; i < 16; ++i) {
        int p = (i & 3) + 8 * (i >> 2) + 4 * h;
        c1[i] = s_e[p];
        c2[i] = b2[p];
    }

    // ================= Phase 2: stats(z2) =================
    zero_acc();
    {
        bf16x8 cur0, cur1, nx0 = {}, nx1 = {};
        int i = 0;
        if (K >= 2) {
            cur0 = loadxb(gwave);
            cur1 = loadxb(gwave + nwaves);
            for (; i + 1 < K; i += 2) {
                int t0 = gwave + i * nwaves;
                if (i + 3 < K) {
                    nx0 = loadxb(t0 + 2 * nwaves);
                    nx1 = loadxb(t0 + 3 * nwaves);
                }
                f32x16 A1 = __builtin_amdgcn_mfma_f32_32x32x16_bf16(w1f, cur0, c1, 0, 0, 0);
                f32x16 B1 = __builtin_amdgcn_mfma_f32_32x32x16_bf16(w1f, cur1, c1, 0, 0, 0);
                bf16x8 qa0, qb0, qa1, qb1;
                rp(A1, qa0, qb0);
                rp(B1, qa1, qb1);
                f32x16 A2 = __builtin_amdgcn_mfma_f32_32x32x16_bf16(w2f0, qa0, c2, 0, 0, 0);
                f32x16 B2 = __builtin_amdgcn_mfma_f32_32x32x16_bf16(w2f0, qa1, c2, 0, 0, 0);
                A2 = __builtin_amdgcn_mfma_f32_32x32x16_bf16(w2f1, qb0, A2, 0, 0, 0);
                B2 = __builtin_amdgcn_mfma_f32_32x32x16_bf16(w2f1, qb1, B2, 0, 0, 0);
                accum2(A2, B2);
                cur0 = nx0; cur1 = nx1;
            }
        }
        for (int t = gwave + i * nwaves; t < ntiles; t += nwaves) {
            bf16x8 xf = loadxb(t);
            f32x16 A1 = __builtin_amdgcn_mfma_f32_32x32x16_bf16(w1f, xf, c1, 0, 0, 0);
            bf16x8 qa, qb;
            rp(A1, qa, qb);
            f32x16 A2 = __builtin_amdgcn_mfma_f32_32x32x16_bf16(w2f0, qa, c2, 0, 0, 0);
            A2 = __builtin_amdgcn_mfma_f32_32x32x16_bf16(w2f1, qb, A2, 0, 0, 0);
            accum1(A2);
        }
    }
    flush(1);
    gbarrier(cnt, 2 * NBLK, tid);
    derive(1, g2, be2, b2);

    bf16x8 w3f0, w3f1;
    build_wf(W3, w3f0, w3f1);
    f32x16 c3;
    #pragma unroll
    for (int i = 0; i < 16; ++i) {
        int p = (i & 3) + 8 * (i >> 2) + 4 * h;
        c2[i] = s_e[p];
        c3[i] = b3[p];
    }

    // ================= Phase 3: stats(z3) =================
    zero_acc();
    {
        bf16x8 cur0, cur1, nx0 = {}, nx1 = {};
        int i = 0;
        if (K >= 2) {
            cur0 = loadxb(gwave);
            cur1 = loadxb(gwave + nwaves);
            for (; i + 1 < K; i += 2) {
                int t0 = gwave + i * nwaves;
                if (i + 3 < K) {
                    nx0 = loadxb(t0 + 2 * nwaves);
                    nx1 = loadxb(t0 + 3 * nwaves);
                }
                f32x16 A1 = __builtin_amdgcn_mfma_f32_32x32x16_bf16(w1f, cur0, c1, 0, 0, 0);
                f32x16 B1 = __builtin_amdgcn_mfma_f32_32x32x16_bf16(w1f, cur1, c1, 0, 0, 0);
                bf16x8 qa0, qb0, qa1, qb1;
                rp(A1, qa0, qb0);
                rp(B1, qa1, qb1);
                f32x16 A2 = __builtin_amdgcn_mfma_f32_32x32x16_bf16(w2f0, qa0, c2, 0, 0, 0);
                f32x16 B2 = __builtin_amdgcn_mfma_f32_32x32x16_bf16(w2f0, qa1, c2, 0, 0, 0);
                A2 = __builtin_amdgcn_mfma_f32_32x32x16_bf16(w2f1, qb0, A2, 0, 0, 0);
                B2 = __builtin_amdgcn_mfma_f32_32x32x16_bf16(w2f1, qb1, B2, 0, 0, 0);
                rp(A2, qa0, qb0);
                rp(B2, qa1, qb1);
                f32x16 A3 = __builtin_amdgcn_mfma_f32_32x32x16_bf16(w3f0, qa0, c3, 0, 0, 0);
                f32x16 B3 = __builtin_amdgcn_mfma_f32_32x32x16_bf16(w3f0, qa1, c3, 0, 0, 0);
                A3 = __builtin_amdgcn_mfma_f32_32x32x16_bf16(w3f1, qb0, A3, 0, 0, 0);
                B3 = __builtin_amdgcn_mfma_f32_32x32x16_bf16(w3f1, qb1, B3, 0, 0, 0);
                accum2(A3, B3);
                cur0 = nx0; cur1 = nx1;
            }
        }
        for (int t = gwave + i * nwaves; t < ntiles; t += nwaves) {
            bf16x8 xf = loadxb(t);
            f32x16 A1 = __builtin_amdgcn_mfma_f32_32x32x16_bf16(w1f, xf, c1, 0, 0, 0);
            bf16x8 qa, qb;
            rp(A1, qa, qb);
            f32x16 A2 = __builtin_amdgcn_mfma_f32_32x32x16_bf16(w2f0, qa, c2, 0, 0, 0);
            A2 = __builtin_amdgcn_mfma_f32_32x32x16_bf16(w2f1, qb, A2, 0, 0, 0);
            rp(A2, qa, qb);
            f32x16 A3 = __builtin_amdgcn_mfma_f32_32x32x16_bf16(w3f0, qa, c3, 0, 0, 0);
            A3 = __builtin_amdgcn_mfma_f32_32x32x16_bf16(w3f1, qb, A3, 0, 0, 0);
            accum1(A3);
        }
    }
    flush(2);
    gbarrier(cnt, 3 * NBLK, tid);
    derive(2, g3, be3, b3);

    float w4c[16];
    #pragma unroll
    for (int i = 0; i < 16; ++i) {
        int p = (i & 3) + 8 * (i >> 2) + 4 * h;
        c3[i]  = s_e[p];
        w4c[i] = W4[p] * s_a[p];
    }
    const float b4v = b4[0];

    // ================= Phase 4: output =================
    {
        bf16x8 cur0, cur1, nx0 = {}, nx1 = {};
        int i = 0;
        if (K >= 2) {
            cur0 = loadxb(gwave);
            cur1 = loadxb(gwave + nwaves);
            for (; i + 1 < K; i += 2) {
                int t0 = gwave + i * nwaves;
                if (i + 3 < K) {
                    nx0 = loadxb(t0 + 2 * nwaves);
                    nx1 = loadxb(t0 + 3 * nwaves);
                }
                f32x16 A1 = __builtin_amdgcn_mfma_f32_32x32x16_bf16(w1f, cur0, c1, 0, 0, 0);
                f32x16 B1 = __builtin_amdgcn_mfma_f32_32x32x16_bf16(w1f, cur1, c1, 0, 0, 0);
                bf16x8 qa0, qb0, qa1, qb1;
                rp(A1, qa0, qb0);
                rp(B1, qa1, qb1);
                f32x16 A2 = __builtin_amdgcn_mfma_f32_32x32x16_bf16(w2f0, qa0, c2, 0, 0, 0);
                f32x16 B2 = __builtin_amdgcn_mfma_f32_32x32x16_bf16(w2f0, qa1, c2, 0, 0, 0);
                A2 = __builtin_amdgcn_mfma_f32_32x32x16_bf16(w2f1, qb0, A2, 0, 0, 0);
                B2 = __builtin_amdgcn_mfma_f32_32x32x16_bf16(w2f1, qb1, B2, 0, 0, 0);
                rp(A2, qa0, qb0);
                rp(B2, qa1, qb1);
                f32x16 A3 = __builtin_amdgcn_mfma_f32_32x32x16_bf16(w3f0, qa0, c3, 0, 0, 0);
                f32x16 B3 = __builtin_amdgcn_mfma_f32_32x32x16_bf16(w3f0, qa1, c3, 0, 0, 0);
                A3 = __builtin_amdgcn_mfma_f32_32x32x16_bf16(w3f1, qb0, A3, 0, 0, 0);
                B3 = __builtin_amdgcn_mfma_f32_32x32x16_bf16(w3f1, qb1, B3, 0, 0, 0);
                float oA = 0.f, oB = 0.f;
                #pragma unroll
                for (int k2 = 0; k2 < 16; ++k2) {
                    oA = fmaf(w4c[k2], fmaxf(A3[k2], 0.f), oA);
                    oB = fmaf(w4c[k2], fmaxf(B3[k2], 0.f), oB);
                }
                oA += __shfl_xor(oA, 32);
                oB += __shfl_xor(oB, 32);
                if (h == 0) {
                    out[(t0 << 5) + ml] = oA + b4v;
                    out[((t0 + nwaves) << 5) + ml] = oB + b4v;
                }
                cur0 = nx0; cur1 = nx1;
            }
        }
        for (int t = gwave + i * nwaves; t < ntiles; t += nwaves) {
            bf16x8 xf = loadxb(t);
            f32x16 A1 = __builtin_amdgcn_mfma_f32_32x32x16_bf16(w1f, xf, c1, 0, 0, 0);
            bf16x8 qa, qb;
            rp(A1, qa, qb);
            f32x16 A2 = __builtin_amdgcn_mfma_f32_32x32x16_bf16(w2f0, qa, c2, 0, 0, 0);
            A2 = __builtin_amdgcn_mfma_f32_32x32x16_bf16(w2f1, qb, A2, 0, 0, 0);
            rp(A2, qa, qb);
            f32x16 A3 = __builtin_amdgcn_mfma_f32_32x32x16_bf16(w3f0, qa, c3, 0, 0, 0);
            A3 = __builtin_amdgcn_mfma_f32_32x32x16_bf16(w3f1, qb, A3, 0, 0, 0);
            float o = 0.f;
            #pragma unroll
            for (int k2 = 0; k2 < 16; ++k2) o = fmaf(w4c[k2], fmaxf(A3[k2], 0.f), o);
            o += __shfl_xor(o, 32);
            if (h == 0) out[(t << 5) + ml] = o + b4v;
        }
    }
}

extern "C" void kernel_launch(void* const* d_in, const int* in_sizes, int n_in,
                              void* d_out, int out_size, void* d_ws, size_t ws_size,
                              hipStream_t stream) {
    const float* x   = (const float*)d_in[0];
    const float* W1  = (const float*)d_in[1];
    const float* b1  = (const float*)d_in[2];
    const float* g1  = (const float*)d_in[3];
    const float* be1 = (const float*)d_in[4];
    const float* W2  = (const float*)d_in[5];
    const float* b2  = (const float*)d_in[6];
    const float* g2  = (const float*)d_in[7];
    const float* be2 = (const float*)d_in[8];
    const float* W3  = (const float*)d_in[9];
    const float* b3  = (const float*)d_in[10];
    const float* g3  = (const float*)d_in[11];
    const float* be3 = (const float*)d_in[12];
    const float* W4  = (const float*)d_in[13];
    const float* b4  = (const float*)d_in[14];
    float* out = (float*)d_out;
    int N = in_sizes[0] / 16;

    __bf16* xb    = (__bf16*)d_ws;
    char* ctrl    = (char*)d_ws + (size_t)N * 32;
    float* stats  = (float*)ctrl;
    unsigned* cnt = (unsigned*)(ctrl + 3 * NSLOT * 64 * sizeof(float));

    hipMemsetAsync(ctrl, 0, 8192, stream);

    k_all<<<NBLK, NTHR, 0, stream>>>(x, xb, W1, b1, g1, be1, W2, b2, g2, be2,
                                     W3, b3, g3, be3, W4, b4, stats, cnt, out, N);
}